// Round 7
// baseline (680.826 us; speedup 1.0000x reference)
//
#include <hip/hip_runtime.h>

#define NN 100000
#define EE 1600000
#define EPSV 1e-5f

// fp32 -> bf16 with round-to-nearest-even (no __hip_bfloat16 dependency)
__device__ __forceinline__ unsigned short f2bf(float f) {
    union { float f; unsigned int u; } cv;
    cv.f = f;
    unsigned int u = cv.u;
    u += 0x7FFFu + ((u >> 16) & 1u);
    return (unsigned short)(u >> 16);
}

__device__ __forceinline__ float bf2f(unsigned short u) {
    union { unsigned int i; float f; } cv;
    cv.i = ((unsigned int)u) << 16;
    return cv.f;
}

// ================= degree histogram (int) =================
__global__ void deg_kernel(const int* __restrict__ dst, int* __restrict__ degi) {
    int e = blockIdx.x * 256 + threadIdx.x;
    if (e < EE) atomicAdd(&degi[dst[e]], 1);
}

__global__ void dinv_kernel(const int* __restrict__ degi, float* __restrict__ dinv) {
    int n = blockIdx.x * 256 + threadIdx.x;
    if (n < NN) dinv[n] = rsqrtf((float)degi[n] + 1.0f);
}

// ================= 2-level exclusive scan over degi -> offsets =================
__global__ void scan1(const int* __restrict__ degi, int* __restrict__ offsets,
                      int* __restrict__ partial) {
    __shared__ int sdata[256];
    int t = threadIdx.x;
    int n = blockIdx.x * 256 + t;
    int v = (n < NN) ? degi[n] : 0;
    sdata[t] = v;
    __syncthreads();
    for (int off = 1; off < 256; off <<= 1) {
        int x = (t >= off) ? sdata[t - off] : 0;
        __syncthreads();
        sdata[t] += x;
        __syncthreads();
    }
    if (n < NN) offsets[n] = sdata[t] - v;  // exclusive
    if (t == 255) partial[blockIdx.x] = sdata[255];
}

__global__ void scan2(int* __restrict__ partial, int* __restrict__ partial_pref, int nparts) {
    __shared__ int sdata[512];
    int t = threadIdx.x;
    int v = (t < nparts) ? partial[t] : 0;
    sdata[t] = v;
    __syncthreads();
    for (int off = 1; off < 512; off <<= 1) {
        int x = (t >= off) ? sdata[t - off] : 0;
        __syncthreads();
        sdata[t] += x;
        __syncthreads();
    }
    if (t < nparts) partial_pref[t] = sdata[t] - v;  // exclusive
}

__global__ void scan3(int* __restrict__ offsets, const int* __restrict__ partial_pref) {
    int n = blockIdx.x * 256 + threadIdx.x;
    if (n < NN) offsets[n] += partial_pref[n >> 8];
}

// ================= CSR fill: counting-sort edges by dst (4B src-only records) ==
// offsets[] doubles as cursor: after fill, offsets[n]==end; start = end - degi[n].
// coef is recomputed in agg (dinv[d] is the wave's own node there).
__global__ void fill_kernel(const int* __restrict__ src, const int* __restrict__ dst,
                            int* __restrict__ offsets, int* __restrict__ sorted) {
    int e = blockIdx.x * 256 + threadIdx.x;
    if (e >= EE) return;
    int s = src[e], d = dst[e];
    int idx = atomicAdd(&offsets[d], 1);
    sorted[idx] = s;
}

// ================= input projection: h = relu(x @ W_in + b_in) =================
__global__ void input_proj(const float* __restrict__ x, const float* __restrict__ Win,
                           const float* __restrict__ bin, float* __restrict__ h) {
    __shared__ float Ws[320];
    __shared__ float bs[64];
    int t = threadIdx.x;
    for (int i = t; i < 320; i += 256) Ws[i] = Win[i];
    if (t < 64) bs[t] = bin[t];
    __syncthreads();
    int n = blockIdx.x * 4 + (t >> 6);
    int c = t & 63;
    if (n >= NN) return;
    float acc = bs[c];
#pragma unroll
    for (int k = 0; k < 5; ++k) acc += x[n * 5 + k] * Ws[k * 64 + c];
    h[n * 64 + c] = fmaxf(acc, 0.f);
}

// ================= hw(bf16) = BNrelu(in) @ W (64x64), BN fused in load =======
__global__ __launch_bounds__(256) void gemm64_bn(const float* __restrict__ in,
                                                 const float* __restrict__ stats,
                                                 const float* __restrict__ gamma,
                                                 const float* __restrict__ beta,
                                                 const float* __restrict__ W,
                                                 unsigned short* __restrict__ out,
                                                 int apply_bn) {
    __shared__ __align__(16) float Ws[4096];
    __shared__ float Hs[64 * 65];
    __shared__ float scale[64], shift[64];
    int t = threadIdx.x;
    if (t < 64) {
        if (apply_bn) {
            const float invN = 1.0f / (float)NN;
            float mean = stats[t] * invN;
            float var = stats[64 + t] * invN - mean * mean;
            float rstd = rsqrtf(var + EPSV);
            float sc = gamma[t] * rstd;
            scale[t] = sc;
            shift[t] = beta[t] - mean * sc;
        } else {
            scale[t] = 1.f;
            shift[t] = 0.f;
        }
    }
    for (int i = t; i < 4096; i += 256) Ws[i] = W[i];
    __syncthreads();
    int base = blockIdx.x * 64;
    for (int i = t; i < 4096; i += 256) {
        int r = i >> 6, c = i & 63;
        float v = 0.f;
        if (base + r < NN) {
            v = in[(base + r) * 64 + c];
            if (apply_bn) v = fmaxf(v * scale[c] + shift[c], 0.f);
        }
        Hs[r * 65 + c] = v;
    }
    __syncthreads();
    int c0 = (t & 15) * 4;
    int r0 = (t >> 4) * 4;
    float acc[4][4] = {};
    for (int k = 0; k < 64; ++k) {
        float4 w = *(const float4*)&Ws[k * 64 + c0];
        float hv[4];
#pragma unroll
        for (int j = 0; j < 4; ++j) hv[j] = Hs[(r0 + j) * 65 + k];
#pragma unroll
        for (int j = 0; j < 4; ++j) {
            acc[j][0] += hv[j] * w.x;
            acc[j][1] += hv[j] * w.y;
            acc[j][2] += hv[j] * w.z;
            acc[j][3] += hv[j] * w.w;
        }
    }
#pragma unroll
    for (int j = 0; j < 4; ++j) {
        int n = base + r0 + j;
        if (n < NN) {
            ushort4 pk;
            pk.x = f2bf(acc[j][0]);
            pk.y = f2bf(acc[j][1]);
            pk.z = f2bf(acc[j][2]);
            pk.w = f2bf(acc[j][3]);
            *(ushort4*)&out[n * 64 + c0] = pk;
        }
    }
}

// ================= CSR gather aggregation (bf16 rows) + fused BN stats ========
// agg[n,c] = hw[n,c]*dinv[n]^2 + b[c] + sum_j hw[src_j,c]*dinv[src_j]*dinv[n]
__global__ __launch_bounds__(256) void agg_kernel(const unsigned short* __restrict__ hw,
                                                  const int* __restrict__ sorted,
                                                  const int* __restrict__ offsets,
                                                  const int* __restrict__ degi,
                                                  const float* __restrict__ dinv,
                                                  const float* __restrict__ b,
                                                  float* __restrict__ agg,
                                                  float* __restrict__ stats) {
    int t = threadIdx.x;
    int c = t & 63;
    int w = t >> 6;
    float bc = b[c];
    float bsum = 0.f, bss = 0.f;
    for (int n = blockIdx.x * 4 + w; n < NN; n += gridDim.x * 4) {
        int cnt = degi[n];
        int start = offsets[n] - cnt;
        float di = dinv[n];
        float acc = bf2f(hw[n * 64 + c]) * (di * di) + bc;
        for (int base = 0; base < cnt; base += 64) {
            int m = min(64, cnt - base);
            int sv = 0;
            float cv = 0.f;
            if (c < m) {
                sv = sorted[start + base + c];
                cv = dinv[sv] * di;   // dinv[s] * dinv[d]; d == n for this wave
            }
            int k = 0;
            for (; k + 4 <= m; k += 4) {
                int s0 = __shfl(sv, k);
                int s1 = __shfl(sv, k + 1);
                int s2 = __shfl(sv, k + 2);
                int s3 = __shfl(sv, k + 3);
                float c0 = __shfl(cv, k);
                float c1 = __shfl(cv, k + 1);
                float c2 = __shfl(cv, k + 2);
                float c3 = __shfl(cv, k + 3);
                float v0 = bf2f(hw[s0 * 64 + c]);
                float v1 = bf2f(hw[s1 * 64 + c]);
                float v2 = bf2f(hw[s2 * 64 + c]);
                float v3 = bf2f(hw[s3 * 64 + c]);
                acc += v0 * c0;
                acc += v1 * c1;
                acc += v2 * c2;
                acc += v3 * c3;
            }
            for (; k < m; ++k) {
                int s = __shfl(sv, k);
                float cf = __shfl(cv, k);
                acc += bf2f(hw[s * 64 + c]) * cf;
            }
        }
        agg[n * 64 + c] = acc;
        bsum += acc;
        bss += acc * acc;
    }
    __shared__ float red[2][4][64];
    red[0][w][c] = bsum;
    red[1][w][c] = bss;
    __syncthreads();
    if (w == 0) {
        float s = red[0][0][c] + red[0][1][c] + red[0][2][c] + red[0][3][c];
        float ss = red[1][0][c] + red[1][1][c] + red[1][2][c] + red[1][3][c];
        atomicAdd(&stats[c], s);
        atomicAdd(&stats[64 + c], ss);
    }
}

// ================= classifier: relu(BN(agg)@W1+b1)@W2 + b2, BN fused =========
__global__ __launch_bounds__(256) void classifier(const float* __restrict__ agg,
                                                  const float* __restrict__ stats,
                                                  const float* __restrict__ gamma,
                                                  const float* __restrict__ beta,
                                                  const float* __restrict__ W1,
                                                  const float* __restrict__ b1,
                                                  const float* __restrict__ W2,
                                                  const float* __restrict__ b2,
                                                  float* __restrict__ out) {
    __shared__ float W1s[2048];
    __shared__ float b1s[32];
    __shared__ float W2s[32];
    __shared__ float scale[64], shift[64];
    int t = threadIdx.x;
    for (int i = t; i < 2048; i += 256) W1s[i] = W1[i];
    if (t < 32) {
        b1s[t] = b1[t];
        W2s[t] = W2[t];
    }
    if (t < 64) {
        const float invN = 1.0f / (float)NN;
        float mean = stats[t] * invN;
        float var = stats[64 + t] * invN - mean * mean;
        float rstd = rsqrtf(var + EPSV);
        float sc = gamma[t] * rstd;
        scale[t] = sc;
        shift[t] = beta[t] - mean * sc;
    }
    __syncthreads();
    int n = blockIdx.x * 256 + t;
    if (n >= NN) return;
    float4 h4[16];
    const float4* hp = (const float4*)(agg + n * 64);
#pragma unroll
    for (int i = 0; i < 16; ++i) h4[i] = hp[i];
    float* hr = (float*)h4;
#pragma unroll
    for (int k = 0; k < 64; ++k) hr[k] = fmaxf(hr[k] * scale[k] + shift[k], 0.f);
    float o = b2[0];
    for (int c = 0; c < 32; ++c) {
        float z = b1s[c];
#pragma unroll
        for (int k = 0; k < 64; ++k) z += hr[k] * W1s[k * 32 + c];
        o += fmaxf(z, 0.f) * W2s[c];
    }
    out[n] = o;
}

extern "C" void kernel_launch(void* const* d_in, const int* in_sizes, int n_in,
                              void* d_out, int out_size, void* d_ws, size_t ws_size,
                              hipStream_t stream) {
    const float* x    = (const float*)d_in[0];
    const int*   ei   = (const int*)d_in[1];
    const float* Win  = (const float*)d_in[2];
    const float* bin  = (const float*)d_in[3];
    const float* cW   = (const float*)d_in[4];
    const float* cb   = (const float*)d_in[5];
    const float* gam  = (const float*)d_in[6];
    const float* bet  = (const float*)d_in[7];
    const float* W1   = (const float*)d_in[8];
    const float* b1   = (const float*)d_in[9];
    const float* W2   = (const float*)d_in[10];
    const float* b2   = (const float*)d_in[11];
    float* out = (float*)d_out;

    // ---- workspace layout ----
    float* h     = (float*)d_ws;                         // NN*64 fp32
    unsigned short* hw = (unsigned short*)(h + NN * 64); // NN*64 bf16 (= NN*32 floats)
    float* agg   = h + NN * 64 + NN * 32;                // NN*64 fp32
    float* dinv  = agg + NN * 64;                        // NN
    float* stats = dinv + NN;                            // 3*128
    int*  degi        = (int*)(stats + 3 * 128);         // NN
    int*  offsets     = degi + NN;                       // NN
    int*  sorted      = offsets + NN;                    // EE int

    // scan temporaries aliased into agg (unused until layer loop)
    int* partial      = (int*)agg;        // 512
    int* partial_pref = (int*)agg + 512;  // 512

    const int* src = ei;
    const int* dst = ei + EE;

    const int NB = (NN + 255) / 256;  // 391

    (void)hipMemsetAsync(degi, 0, NN * sizeof(int), stream);
    (void)hipMemsetAsync(stats, 0, 3 * 128 * sizeof(float), stream);

    deg_kernel<<<(EE + 255) / 256, 256, 0, stream>>>(dst, degi);
    dinv_kernel<<<NB, 256, 0, stream>>>(degi, dinv);
    scan1<<<NB, 256, 0, stream>>>(degi, offsets, partial);
    scan2<<<1, 512, 0, stream>>>(partial, partial_pref, NB);
    scan3<<<NB, 256, 0, stream>>>(offsets, partial_pref);
    fill_kernel<<<(EE + 255) / 256, 256, 0, stream>>>(src, dst, offsets, sorted);
    input_proj<<<(NN + 3) / 4, 256, 0, stream>>>(x, Win, bin, h);

    for (int i = 0; i < 3; ++i) {
        const float* gin = (i == 0) ? h : agg;
        const float* gst = stats + (i - 1) * 128;  // only read when i>0
        gemm64_bn<<<(NN + 63) / 64, 256, 0, stream>>>(gin, gst, gam + (i - 1) * 64,
                                                      bet + (i - 1) * 64, cW + i * 4096,
                                                      hw, i > 0 ? 1 : 0);
        agg_kernel<<<2048, 256, 0, stream>>>(hw, sorted, offsets, degi, dinv,
                                             cb + i * 64, agg, stats + i * 128);
    }

    classifier<<<(NN + 255) / 256, 256, 0, stream>>>(agg, stats + 2 * 128, gam + 2 * 64,
                                                     bet + 2 * 64, W1, b1, W2, b2, out);
}

// Round 8
// 604.561 us; speedup vs baseline: 1.1261x; 1.1261x over previous
//
#include <hip/hip_runtime.h>

#define NN 100000
#define EE 1600000
#define EPSV 1e-5f

// fp32 -> bf16 round-to-nearest-even
__device__ __forceinline__ unsigned short f2bf(float f) {
    union { float f; unsigned int u; } cv;
    cv.f = f;
    unsigned int u = cv.u;
    u += 0x7FFFu + ((u >> 16) & 1u);
    return (unsigned short)(u >> 16);
}

__device__ __forceinline__ float bf2f(unsigned short u) {
    union { unsigned int i; float f; } cv;
    cv.i = ((unsigned int)u) << 16;
    return cv.f;
}

// ================= degree histogram (int) =================
__global__ void deg_kernel(const int* __restrict__ dst, int* __restrict__ degi) {
    int e = blockIdx.x * 256 + threadIdx.x;
    if (e < EE) atomicAdd(&degi[dst[e]], 1);
}

__global__ void dinv_kernel(const int* __restrict__ degi, float* __restrict__ dinv) {
    int n = blockIdx.x * 256 + threadIdx.x;
    if (n < NN) dinv[n] = rsqrtf((float)degi[n] + 1.0f);
}

// ================= 2-level exclusive scan over degi -> offsets =================
__global__ void scan1(const int* __restrict__ degi, int* __restrict__ offsets,
                      int* __restrict__ partial) {
    __shared__ int sdata[256];
    int t = threadIdx.x;
    int n = blockIdx.x * 256 + t;
    int v = (n < NN) ? degi[n] : 0;
    sdata[t] = v;
    __syncthreads();
    for (int off = 1; off < 256; off <<= 1) {
        int x = (t >= off) ? sdata[t - off] : 0;
        __syncthreads();
        sdata[t] += x;
        __syncthreads();
    }
    if (n < NN) offsets[n] = sdata[t] - v;  // exclusive
    if (t == 255) partial[blockIdx.x] = sdata[255];
}

__global__ void scan2(int* __restrict__ partial, int* __restrict__ partial_pref, int nparts) {
    __shared__ int sdata[512];
    int t = threadIdx.x;
    int v = (t < nparts) ? partial[t] : 0;
    sdata[t] = v;
    __syncthreads();
    for (int off = 1; off < 512; off <<= 1) {
        int x = (t >= off) ? sdata[t - off] : 0;
        __syncthreads();
        sdata[t] += x;
        __syncthreads();
    }
    if (t < nparts) partial_pref[t] = sdata[t] - v;  // exclusive
}

__global__ void scan3(int* __restrict__ offsets, const int* __restrict__ partial_pref) {
    int n = blockIdx.x * 256 + threadIdx.x;
    if (n < NN) offsets[n] += partial_pref[n >> 8];
}

// ================= CSR fill: counting-sort edges by dst (int2 records) ========
// offsets[] doubles as cursor: after fill, offsets[n]==end; start = end - degi[n].
__global__ void fill_kernel(const int* __restrict__ src, const int* __restrict__ dst,
                            int* __restrict__ offsets, const float* __restrict__ dinv,
                            int2* __restrict__ sorted) {
    int e = blockIdx.x * 256 + threadIdx.x;
    if (e >= EE) return;
    int s = src[e], d = dst[e];
    int idx = atomicAdd(&offsets[d], 1);
    int2 rec;
    rec.x = s;
    rec.y = __float_as_int(dinv[s] * dinv[d]);
    sorted[idx] = rec;
}

// ================= hw(bf16) = act(in) @ W (64x64) ============================
// mode 0: act = relu(x @ Win + bin)   (input projection fused; in unused)
// mode 1: act = relu(BN(in))          (in = agg of previous layer)
__global__ __launch_bounds__(256) void gemm64_bn(const float* __restrict__ in,
                                                 const float* __restrict__ x,
                                                 const float* __restrict__ Win,
                                                 const float* __restrict__ bin,
                                                 const float* __restrict__ stats,
                                                 const float* __restrict__ gamma,
                                                 const float* __restrict__ beta,
                                                 const float* __restrict__ W,
                                                 unsigned short* __restrict__ out,
                                                 int mode) {
    __shared__ __align__(16) float Ws[4096];
    __shared__ float Hs[64 * 65];
    __shared__ float scale[64], shift[64];
    __shared__ float Wins[320];
    __shared__ float bins[64];
    int t = threadIdx.x;
    if (mode == 1) {
        if (t < 64) {
            const float invN = 1.0f / (float)NN;
            float mean = stats[t] * invN;
            float var = stats[64 + t] * invN - mean * mean;
            float rstd = rsqrtf(var + EPSV);
            float sc = gamma[t] * rstd;
            scale[t] = sc;
            shift[t] = beta[t] - mean * sc;
        }
    } else {
        for (int i = t; i < 320; i += 256) Wins[i] = Win[i];
        if (t < 64) bins[t] = bin[t];
    }
    for (int i = t; i < 4096; i += 256) Ws[i] = W[i];
    __syncthreads();
    int base = blockIdx.x * 64;
    if (mode == 1) {
        for (int i = t; i < 4096; i += 256) {
            int r = i >> 6, c = i & 63;
            float v = 0.f;
            if (base + r < NN) {
                v = in[(base + r) * 64 + c];
                v = fmaxf(v * scale[c] + shift[c], 0.f);
            }
            Hs[r * 65 + c] = v;
        }
    } else {
        for (int i = t; i < 4096; i += 256) {
            int r = i >> 6, c = i & 63;
            int n = base + r;
            float v = 0.f;
            if (n < NN) {
                float acc = bins[c];
#pragma unroll
                for (int k = 0; k < 5; ++k) acc += x[n * 5 + k] * Wins[k * 64 + c];
                v = fmaxf(acc, 0.f);
            }
            Hs[r * 65 + c] = v;
        }
    }
    __syncthreads();
    int c0 = (t & 15) * 4;
    int r0 = (t >> 4) * 4;
    float acc[4][4] = {};
    for (int k = 0; k < 64; ++k) {
        float4 w = *(const float4*)&Ws[k * 64 + c0];
        float hv[4];
#pragma unroll
        for (int j = 0; j < 4; ++j) hv[j] = Hs[(r0 + j) * 65 + k];
#pragma unroll
        for (int j = 0; j < 4; ++j) {
            acc[j][0] += hv[j] * w.x;
            acc[j][1] += hv[j] * w.y;
            acc[j][2] += hv[j] * w.z;
            acc[j][3] += hv[j] * w.w;
        }
    }
#pragma unroll
    for (int j = 0; j < 4; ++j) {
        int n = base + r0 + j;
        if (n < NN) {
            ushort4 pk;
            pk.x = f2bf(acc[j][0]);
            pk.y = f2bf(acc[j][1]);
            pk.z = f2bf(acc[j][2]);
            pk.w = f2bf(acc[j][3]);
            *(ushort4*)&out[n * 64 + c0] = pk;
        }
    }
}

// ================= CSR gather aggregation (bf16 rows) + fused BN stats ========
// agg[n,c] = hw[n,c]*dinv[n]^2 + b[c] + sum_j hw[src_j,c]*coef_j
// 8-deep unroll: 8 independent row gathers in flight per wave.
__global__ __launch_bounds__(256) void agg_kernel(const unsigned short* __restrict__ hw,
                                                  const int2* __restrict__ sorted,
                                                  const int* __restrict__ offsets,
                                                  const int* __restrict__ degi,
                                                  const float* __restrict__ dinv,
                                                  const float* __restrict__ b,
                                                  float* __restrict__ agg,
                                                  float* __restrict__ stats) {
    int t = threadIdx.x;
    int c = t & 63;
    int w = t >> 6;
    float bc = b[c];
    float bsum = 0.f, bss = 0.f;
    for (int n = blockIdx.x * 4 + w; n < NN; n += gridDim.x * 4) {
        int cnt = degi[n];
        int start = offsets[n] - cnt;
        float di = dinv[n];
        float acc = bf2f(hw[n * 64 + c]) * (di * di) + bc;
        for (int base = 0; base < cnt; base += 64) {
            int m = min(64, cnt - base);
            int2 rec = make_int2(0, 0);
            if (c < m) rec = sorted[start + base + c];
            int k = 0;
            for (; k + 8 <= m; k += 8) {
                int s0 = __shfl(rec.x, k);
                int s1 = __shfl(rec.x, k + 1);
                int s2 = __shfl(rec.x, k + 2);
                int s3 = __shfl(rec.x, k + 3);
                int s4 = __shfl(rec.x, k + 4);
                int s5 = __shfl(rec.x, k + 5);
                int s6 = __shfl(rec.x, k + 6);
                int s7 = __shfl(rec.x, k + 7);
                float v0 = bf2f(hw[s0 * 64 + c]);
                float v1 = bf2f(hw[s1 * 64 + c]);
                float v2 = bf2f(hw[s2 * 64 + c]);
                float v3 = bf2f(hw[s3 * 64 + c]);
                float v4 = bf2f(hw[s4 * 64 + c]);
                float v5 = bf2f(hw[s5 * 64 + c]);
                float v6 = bf2f(hw[s6 * 64 + c]);
                float v7 = bf2f(hw[s7 * 64 + c]);
                float c0 = __int_as_float(__shfl(rec.y, k));
                float c1 = __int_as_float(__shfl(rec.y, k + 1));
                float c2 = __int_as_float(__shfl(rec.y, k + 2));
                float c3 = __int_as_float(__shfl(rec.y, k + 3));
                float c4 = __int_as_float(__shfl(rec.y, k + 4));
                float c5 = __int_as_float(__shfl(rec.y, k + 5));
                float c6 = __int_as_float(__shfl(rec.y, k + 6));
                float c7 = __int_as_float(__shfl(rec.y, k + 7));
                acc += v0 * c0;
                acc += v1 * c1;
                acc += v2 * c2;
                acc += v3 * c3;
                acc += v4 * c4;
                acc += v5 * c5;
                acc += v6 * c6;
                acc += v7 * c7;
            }
            for (; k < m; ++k) {
                int s = __shfl(rec.x, k);
                float cf = __int_as_float(__shfl(rec.y, k));
                acc += bf2f(hw[s * 64 + c]) * cf;
            }
        }
        agg[n * 64 + c] = acc;
        bsum += acc;
        bss += acc * acc;
    }
    __shared__ float red[2][4][64];
    red[0][w][c] = bsum;
    red[1][w][c] = bss;
    __syncthreads();
    if (w == 0) {
        float s = red[0][0][c] + red[0][1][c] + red[0][2][c] + red[0][3][c];
        float ss = red[1][0][c] + red[1][1][c] + red[1][2][c] + red[1][3][c];
        atomicAdd(&stats[c], s);
        atomicAdd(&stats[64 + c], ss);
    }
}

// ================= classifier: relu(BN(agg)@W1+b1)@W2 + b2, BN fused =========
__global__ __launch_bounds__(256) void classifier(const float* __restrict__ agg,
                                                  const float* __restrict__ stats,
                                                  const float* __restrict__ gamma,
                                                  const float* __restrict__ beta,
                                                  const float* __restrict__ W1,
                                                  const float* __restrict__ b1,
                                                  const float* __restrict__ W2,
                                                  const float* __restrict__ b2,
                                                  float* __restrict__ out) {
    __shared__ float W1s[2048];
    __shared__ float b1s[32];
    __shared__ float W2s[32];
    __shared__ float scale[64], shift[64];
    int t = threadIdx.x;
    for (int i = t; i < 2048; i += 256) W1s[i] = W1[i];
    if (t < 32) {
        b1s[t] = b1[t];
        W2s[t] = W2[t];
    }
    if (t < 64) {
        const float invN = 1.0f / (float)NN;
        float mean = stats[t] * invN;
        float var = stats[64 + t] * invN - mean * mean;
        float rstd = rsqrtf(var + EPSV);
        float sc = gamma[t] * rstd;
        scale[t] = sc;
        shift[t] = beta[t] - mean * sc;
    }
    __syncthreads();
    int n = blockIdx.x * 256 + t;
    if (n >= NN) return;
    float4 h4[16];
    const float4* hp = (const float4*)(agg + n * 64);
#pragma unroll
    for (int i = 0; i < 16; ++i) h4[i] = hp[i];
    float* hr = (float*)h4;
#pragma unroll
    for (int k = 0; k < 64; ++k) hr[k] = fmaxf(hr[k] * scale[k] + shift[k], 0.f);
    float o = b2[0];
    for (int c = 0; c < 32; ++c) {
        float z = b1s[c];
#pragma unroll
        for (int k = 0; k < 64; ++k) z += hr[k] * W1s[k * 32 + c];
        o += fmaxf(z, 0.f) * W2s[c];
    }
    out[n] = o;
}

extern "C" void kernel_launch(void* const* d_in, const int* in_sizes, int n_in,
                              void* d_out, int out_size, void* d_ws, size_t ws_size,
                              hipStream_t stream) {
    const float* x    = (const float*)d_in[0];
    const int*   ei   = (const int*)d_in[1];
    const float* Win  = (const float*)d_in[2];
    const float* bin  = (const float*)d_in[3];
    const float* cW   = (const float*)d_in[4];
    const float* cb   = (const float*)d_in[5];
    const float* gam  = (const float*)d_in[6];
    const float* bet  = (const float*)d_in[7];
    const float* W1   = (const float*)d_in[8];
    const float* b1   = (const float*)d_in[9];
    const float* W2   = (const float*)d_in[10];
    const float* b2   = (const float*)d_in[11];
    float* out = (float*)d_out;

    // ---- workspace layout ----
    unsigned short* hw = (unsigned short*)d_ws;          // NN*64 bf16 (= NN*32 floats)
    float* agg   = (float*)d_ws + NN * 32;               // NN*64 fp32
    float* dinv  = agg + NN * 64;                        // NN
    float* stats = dinv + NN;                            // 3*128
    int*  degi        = (int*)(stats + 3 * 128);         // NN
    int*  offsets     = degi + NN;                       // NN
    int2* sorted      = (int2*)(offsets + NN);           // EE int2

    // scan temporaries aliased into agg (only used before layer loop)
    int* partial      = (int*)agg;        // 512
    int* partial_pref = (int*)agg + 512;  // 512

    const int* src = ei;
    const int* dst = ei + EE;

    const int NB = (NN + 255) / 256;  // 391

    (void)hipMemsetAsync(degi, 0, NN * sizeof(int), stream);
    (void)hipMemsetAsync(stats, 0, 3 * 128 * sizeof(float), stream);

    deg_kernel<<<(EE + 255) / 256, 256, 0, stream>>>(dst, degi);
    dinv_kernel<<<NB, 256, 0, stream>>>(degi, dinv);
    scan1<<<NB, 256, 0, stream>>>(degi, offsets, partial);
    scan2<<<1, 512, 0, stream>>>(partial, partial_pref, NB);
    scan3<<<NB, 256, 0, stream>>>(offsets, partial_pref);
    fill_kernel<<<(EE + 255) / 256, 256, 0, stream>>>(src, dst, offsets, dinv, sorted);

    for (int i = 0; i < 3; ++i) {
        gemm64_bn<<<(NN + 63) / 64, 256, 0, stream>>>(
            agg, x, Win, bin, stats + (i - 1) * 128, gam + (i - 1) * 64,
            bet + (i - 1) * 64, cW + i * 4096, hw, i > 0 ? 1 : 0);
        agg_kernel<<<2048, 256, 0, stream>>>(hw, sorted, offsets, degi, dinv,
                                             cb + i * 64, agg, stats + i * 128);
    }

    classifier<<<(NN + 255) / 256, 256, 0, stream>>>(agg, stats + 2 * 128, gam + 2 * 64,
                                                     bet + 2 * 64, W1, b1, W2, b2, out);
}

// Round 9
// 594.458 us; speedup vs baseline: 1.1453x; 1.0170x over previous
//
#include <hip/hip_runtime.h>

#define NN 100000
#define EE 1600000
#define EPSV 1e-5f

// fp32 -> bf16 round-to-nearest-even
__device__ __forceinline__ unsigned short f2bf(float f) {
    union { float f; unsigned int u; } cv;
    cv.f = f;
    unsigned int u = cv.u;
    u += 0x7FFFu + ((u >> 16) & 1u);
    return (unsigned short)(u >> 16);
}

__device__ __forceinline__ float bf2f(unsigned short u) {
    union { unsigned int i; float f; } cv;
    cv.i = ((unsigned int)u) << 16;
    return cv.f;
}

// ================= degree histogram (int) =================
__global__ void deg_kernel(const int* __restrict__ dst, int* __restrict__ degi) {
    int e = blockIdx.x * 256 + threadIdx.x;
    if (e < EE) atomicAdd(&degi[dst[e]], 1);
}

__global__ void dinv_kernel(const int* __restrict__ degi, float* __restrict__ dinv) {
    int n = blockIdx.x * 256 + threadIdx.x;
    if (n < NN) dinv[n] = rsqrtf((float)degi[n] + 1.0f);
}

// ================= 2-level exclusive scan over degi -> offsets =================
__global__ void scan1(const int* __restrict__ degi, int* __restrict__ offsets,
                      int* __restrict__ partial) {
    __shared__ int sdata[256];
    int t = threadIdx.x;
    int n = blockIdx.x * 256 + t;
    int v = (n < NN) ? degi[n] : 0;
    sdata[t] = v;
    __syncthreads();
    for (int off = 1; off < 256; off <<= 1) {
        int x = (t >= off) ? sdata[t - off] : 0;
        __syncthreads();
        sdata[t] += x;
        __syncthreads();
    }
    if (n < NN) offsets[n] = sdata[t] - v;  // exclusive
    if (t == 255) partial[blockIdx.x] = sdata[255];
}

__global__ void scan2(int* __restrict__ partial, int* __restrict__ partial_pref, int nparts) {
    __shared__ int sdata[512];
    int t = threadIdx.x;
    int v = (t < nparts) ? partial[t] : 0;
    sdata[t] = v;
    __syncthreads();
    for (int off = 1; off < 512; off <<= 1) {
        int x = (t >= off) ? sdata[t - off] : 0;
        __syncthreads();
        sdata[t] += x;
        __syncthreads();
    }
    if (t < nparts) partial_pref[t] = sdata[t] - v;  // exclusive
}

__global__ void scan3(int* __restrict__ offsets, const int* __restrict__ partial_pref) {
    int n = blockIdx.x * 256 + threadIdx.x;
    if (n < NN) offsets[n] += partial_pref[n >> 8];
}

// ================= CSR fill: counting-sort edges by dst (int2 records) ========
// offsets[] doubles as cursor: after fill, offsets[n]==end; start = end - degi[n].
__global__ void fill_kernel(const int* __restrict__ src, const int* __restrict__ dst,
                            int* __restrict__ offsets, const float* __restrict__ dinv,
                            int2* __restrict__ sorted) {
    int e = blockIdx.x * 256 + threadIdx.x;
    if (e >= EE) return;
    int s = src[e], d = dst[e];
    int idx = atomicAdd(&offsets[d], 1);
    int2 rec;
    rec.x = s;
    rec.y = __float_as_int(dinv[s] * dinv[d]);
    sorted[idx] = rec;
}

// ================= hw(bf16) = act(in) @ W (64x64) ============================
// mode 0: act = relu(x @ Win + bin)   (input projection fused; in unused)
// mode 1: act = relu(BN(in))          (in = agg of previous layer)
__global__ __launch_bounds__(256) void gemm64_bn(const float* __restrict__ in,
                                                 const float* __restrict__ x,
                                                 const float* __restrict__ Win,
                                                 const float* __restrict__ bin,
                                                 const float* __restrict__ stats,
                                                 const float* __restrict__ gamma,
                                                 const float* __restrict__ beta,
                                                 const float* __restrict__ W,
                                                 unsigned short* __restrict__ out,
                                                 int mode) {
    __shared__ __align__(16) float Ws[4096];
    __shared__ float Hs[64 * 65];
    __shared__ float scale[64], shift[64];
    __shared__ float Wins[320];
    __shared__ float bins[64];
    int t = threadIdx.x;
    if (mode == 1) {
        if (t < 64) {
            const float invN = 1.0f / (float)NN;
            float mean = stats[t] * invN;
            float var = stats[64 + t] * invN - mean * mean;
            float rstd = rsqrtf(var + EPSV);
            float sc = gamma[t] * rstd;
            scale[t] = sc;
            shift[t] = beta[t] - mean * sc;
        }
    } else {
        for (int i = t; i < 320; i += 256) Wins[i] = Win[i];
        if (t < 64) bins[t] = bin[t];
    }
    for (int i = t; i < 4096; i += 256) Ws[i] = W[i];
    __syncthreads();
    int base = blockIdx.x * 64;
    if (mode == 1) {
        for (int i = t; i < 4096; i += 256) {
            int r = i >> 6, c = i & 63;
            float v = 0.f;
            if (base + r < NN) {
                v = in[(base + r) * 64 + c];
                v = fmaxf(v * scale[c] + shift[c], 0.f);
            }
            Hs[r * 65 + c] = v;
        }
    } else {
        for (int i = t; i < 4096; i += 256) {
            int r = i >> 6, c = i & 63;
            int n = base + r;
            float v = 0.f;
            if (n < NN) {
                float acc = bins[c];
#pragma unroll
                for (int k = 0; k < 5; ++k) acc += x[n * 5 + k] * Wins[k * 64 + c];
                v = fmaxf(acc, 0.f);
            }
            Hs[r * 65 + c] = v;
        }
    }
    __syncthreads();
    int c0 = (t & 15) * 4;
    int r0 = (t >> 4) * 4;
    float acc[4][4] = {};
    for (int k = 0; k < 64; ++k) {
        float4 w = *(const float4*)&Ws[k * 64 + c0];
        float hv[4];
#pragma unroll
        for (int j = 0; j < 4; ++j) hv[j] = Hs[(r0 + j) * 65 + k];
#pragma unroll
        for (int j = 0; j < 4; ++j) {
            acc[j][0] += hv[j] * w.x;
            acc[j][1] += hv[j] * w.y;
            acc[j][2] += hv[j] * w.z;
            acc[j][3] += hv[j] * w.w;
        }
    }
#pragma unroll
    for (int j = 0; j < 4; ++j) {
        int n = base + r0 + j;
        if (n < NN) {
            ushort4 pk;
            pk.x = f2bf(acc[j][0]);
            pk.y = f2bf(acc[j][1]);
            pk.z = f2bf(acc[j][2]);
            pk.w = f2bf(acc[j][3]);
            *(ushort4*)&out[n * 64 + c0] = pk;
        }
    }
}

// ================= CSR gather aggregation, 2 edges/wave, packed bf16x2 ========
// Half-wave h (lanes 32h..32h+31) processes edges k+h; lane holds channels
// {2*c2, 2*c2+1} as one uint. Records at lanes >= m are (0, coef=0), so
// out-of-range shuffles contribute exactly zero — no guards in the hot loop.
__global__ __launch_bounds__(256) void agg_kernel(const unsigned int* __restrict__ hw32,
                                                  const int2* __restrict__ sorted,
                                                  const int* __restrict__ offsets,
                                                  const int* __restrict__ degi,
                                                  const float* __restrict__ dinv,
                                                  const float* __restrict__ b,
                                                  float* __restrict__ agg,
                                                  float* __restrict__ stats) {
    int t = threadIdx.x;
    int lane = t & 63;
    int w = t >> 6;
    int half = lane >> 5;
    int c2 = lane & 31;  // channel pair: 2*c2, 2*c2+1
    float b0 = b[2 * c2], b1v = b[2 * c2 + 1];
    float bsx = 0.f, bsy = 0.f, bqx = 0.f, bqy = 0.f;
    for (int n = blockIdx.x * 4 + w; n < NN; n += gridDim.x * 4) {
        int cnt = degi[n];
        int start = offsets[n] - cnt;
        float di = dinv[n];
        float ax = 0.f, ay = 0.f;
        if (half == 0) {
            unsigned int u = hw32[n * 32 + c2];
            float sc = di * di;
            ax = bf2f((unsigned short)(u & 0xffffu)) * sc + b0;
            ay = bf2f((unsigned short)(u >> 16)) * sc + b1v;
        }
        for (int base = 0; base < cnt; base += 64) {
            int m = min(64, cnt - base);
            int2 rec = make_int2(0, 0);  // coef bits 0 -> 0.0f
            if (lane < m) rec = sorted[start + base + lane];
            int k = 0;
            // 16-edge unroll: 8 gather instrs, 16 rows in flight per wave
            for (; k + 16 <= m; k += 16) {
                int e0 = k + half, e1 = k + 2 + half, e2 = k + 4 + half, e3 = k + 6 + half;
                int e4 = k + 8 + half, e5 = k + 10 + half, e6 = k + 12 + half, e7 = k + 14 + half;
                int s0 = __shfl(rec.x, e0), s1 = __shfl(rec.x, e1);
                int s2 = __shfl(rec.x, e2), s3 = __shfl(rec.x, e3);
                int s4 = __shfl(rec.x, e4), s5 = __shfl(rec.x, e5);
                int s6 = __shfl(rec.x, e6), s7 = __shfl(rec.x, e7);
                unsigned int u0 = hw32[s0 * 32 + c2];
                unsigned int u1 = hw32[s1 * 32 + c2];
                unsigned int u2 = hw32[s2 * 32 + c2];
                unsigned int u3 = hw32[s3 * 32 + c2];
                unsigned int u4 = hw32[s4 * 32 + c2];
                unsigned int u5 = hw32[s5 * 32 + c2];
                unsigned int u6 = hw32[s6 * 32 + c2];
                unsigned int u7 = hw32[s7 * 32 + c2];
                float c0 = __int_as_float(__shfl(rec.y, e0));
                float c1 = __int_as_float(__shfl(rec.y, e1));
                float c2f = __int_as_float(__shfl(rec.y, e2));
                float c3 = __int_as_float(__shfl(rec.y, e3));
                float c4 = __int_as_float(__shfl(rec.y, e4));
                float c5 = __int_as_float(__shfl(rec.y, e5));
                float c6 = __int_as_float(__shfl(rec.y, e6));
                float c7 = __int_as_float(__shfl(rec.y, e7));
                ax += bf2f((unsigned short)(u0 & 0xffffu)) * c0;
                ay += bf2f((unsigned short)(u0 >> 16)) * c0;
                ax += bf2f((unsigned short)(u1 & 0xffffu)) * c1;
                ay += bf2f((unsigned short)(u1 >> 16)) * c1;
                ax += bf2f((unsigned short)(u2 & 0xffffu)) * c2f;
                ay += bf2f((unsigned short)(u2 >> 16)) * c2f;
                ax += bf2f((unsigned short)(u3 & 0xffffu)) * c3;
                ay += bf2f((unsigned short)(u3 >> 16)) * c3;
                ax += bf2f((unsigned short)(u4 & 0xffffu)) * c4;
                ay += bf2f((unsigned short)(u4 >> 16)) * c4;
                ax += bf2f((unsigned short)(u5 & 0xffffu)) * c5;
                ay += bf2f((unsigned short)(u5 >> 16)) * c5;
                ax += bf2f((unsigned short)(u6 & 0xffffu)) * c6;
                ay += bf2f((unsigned short)(u6 >> 16)) * c6;
                ax += bf2f((unsigned short)(u7 & 0xffffu)) * c7;
                ay += bf2f((unsigned short)(u7 >> 16)) * c7;
            }
            for (; k + 4 <= m; k += 4) {
                int e0 = k + half, e1 = k + 2 + half;
                int s0 = __shfl(rec.x, e0), s1 = __shfl(rec.x, e1);
                unsigned int u0 = hw32[s0 * 32 + c2];
                unsigned int u1 = hw32[s1 * 32 + c2];
                float c0 = __int_as_float(__shfl(rec.y, e0));
                float c1 = __int_as_float(__shfl(rec.y, e1));
                ax += bf2f((unsigned short)(u0 & 0xffffu)) * c0;
                ay += bf2f((unsigned short)(u0 >> 16)) * c0;
                ax += bf2f((unsigned short)(u1 & 0xffffu)) * c1;
                ay += bf2f((unsigned short)(u1 >> 16)) * c1;
            }
            for (; k < m; k += 2) {
                int e = k + half;  // e may reach m (<64): rec there is (0,0) -> adds 0
                int s = __shfl(rec.x, e);
                float cf = __int_as_float(__shfl(rec.y, e));
                unsigned int u = hw32[s * 32 + c2];
                ax += bf2f((unsigned short)(u & 0xffffu)) * cf;
                ay += bf2f((unsigned short)(u >> 16)) * cf;
            }
        }
        // combine the two half-waves
        ax += __shfl_xor(ax, 32);
        ay += __shfl_xor(ay, 32);
        if (half == 0) {
            float2 v = make_float2(ax, ay);
            *(float2*)&agg[n * 64 + 2 * c2] = v;
            bsx += ax;
            bsy += ay;
            bqx += ax * ax;
            bqy += ay * ay;
        }
    }
    __shared__ float red[2][4][64];
    if (half == 0) {
        red[0][w][2 * c2] = bsx;
        red[0][w][2 * c2 + 1] = bsy;
        red[1][w][2 * c2] = bqx;
        red[1][w][2 * c2 + 1] = bqy;
    }
    __syncthreads();
    if (w == 0) {
        int c = t;  // 0..63
        float s = red[0][0][c] + red[0][1][c] + red[0][2][c] + red[0][3][c];
        float ss = red[1][0][c] + red[1][1][c] + red[1][2][c] + red[1][3][c];
        atomicAdd(&stats[c], s);
        atomicAdd(&stats[64 + c], ss);
    }
}

// ================= classifier: relu(BN(agg)@W1+b1)@W2 + b2, BN fused =========
__global__ __launch_bounds__(256) void classifier(const float* __restrict__ agg,
                                                  const float* __restrict__ stats,
                                                  const float* __restrict__ gamma,
                                                  const float* __restrict__ beta,
                                                  const float* __restrict__ W1,
                                                  const float* __restrict__ b1,
                                                  const float* __restrict__ W2,
                                                  const float* __restrict__ b2,
                                                  float* __restrict__ out) {
    __shared__ float W1s[2048];
    __shared__ float b1s[32];
    __shared__ float W2s[32];
    __shared__ float scale[64], shift[64];
    int t = threadIdx.x;
    for (int i = t; i < 2048; i += 256) W1s[i] = W1[i];
    if (t < 32) {
        b1s[t] = b1[t];
        W2s[t] = W2[t];
    }
    if (t < 64) {
        const float invN = 1.0f / (float)NN;
        float mean = stats[t] * invN;
        float var = stats[64 + t] * invN - mean * mean;
        float rstd = rsqrtf(var + EPSV);
        float sc = gamma[t] * rstd;
        scale[t] = sc;
        shift[t] = beta[t] - mean * sc;
    }
    __syncthreads();
    int n = blockIdx.x * 256 + t;
    if (n >= NN) return;
    float4 h4[16];
    const float4* hp = (const float4*)(agg + n * 64);
#pragma unroll
    for (int i = 0; i < 16; ++i) h4[i] = hp[i];
    float* hr = (float*)h4;
#pragma unroll
    for (int k = 0; k < 64; ++k) hr[k] = fmaxf(hr[k] * scale[k] + shift[k], 0.f);
    float o = b2[0];
    for (int c = 0; c < 32; ++c) {
        float z = b1s[c];
#pragma unroll
        for (int k = 0; k < 64; ++k) z += hr[k] * W1s[k * 32 + c];
        o += fmaxf(z, 0.f) * W2s[c];
    }
    out[n] = o;
}

extern "C" void kernel_launch(void* const* d_in, const int* in_sizes, int n_in,
                              void* d_out, int out_size, void* d_ws, size_t ws_size,
                              hipStream_t stream) {
    const float* x    = (const float*)d_in[0];
    const int*   ei   = (const int*)d_in[1];
    const float* Win  = (const float*)d_in[2];
    const float* bin  = (const float*)d_in[3];
    const float* cW   = (const float*)d_in[4];
    const float* cb   = (const float*)d_in[5];
    const float* gam  = (const float*)d_in[6];
    const float* bet  = (const float*)d_in[7];
    const float* W1   = (const float*)d_in[8];
    const float* b1   = (const float*)d_in[9];
    const float* W2   = (const float*)d_in[10];
    const float* b2   = (const float*)d_in[11];
    float* out = (float*)d_out;

    // ---- workspace layout ----
    unsigned short* hw = (unsigned short*)d_ws;          // NN*64 bf16 (= NN*32 floats)
    float* agg   = (float*)d_ws + NN * 32;               // NN*64 fp32
    float* dinv  = agg + NN * 64;                        // NN
    float* stats = dinv + NN;                            // 3*128
    int*  degi        = (int*)(stats + 3 * 128);         // NN
    int*  offsets     = degi + NN;                       // NN
    int2* sorted      = (int2*)(offsets + NN);           // EE int2

    // scan temporaries aliased into agg (only used before layer loop)
    int* partial      = (int*)agg;        // 512
    int* partial_pref = (int*)agg + 512;  // 512

    const int* src = ei;
    const int* dst = ei + EE;

    const int NB = (NN + 255) / 256;  // 391

    (void)hipMemsetAsync(degi, 0, NN * sizeof(int), stream);
    (void)hipMemsetAsync(stats, 0, 3 * 128 * sizeof(float), stream);

    deg_kernel<<<(EE + 255) / 256, 256, 0, stream>>>(dst, degi);
    dinv_kernel<<<NB, 256, 0, stream>>>(degi, dinv);
    scan1<<<NB, 256, 0, stream>>>(degi, offsets, partial);
    scan2<<<1, 512, 0, stream>>>(partial, partial_pref, NB);
    scan3<<<NB, 256, 0, stream>>>(offsets, partial_pref);
    fill_kernel<<<(EE + 255) / 256, 256, 0, stream>>>(src, dst, offsets, dinv, sorted);

    for (int i = 0; i < 3; ++i) {
        gemm64_bn<<<(NN + 63) / 64, 256, 0, stream>>>(
            agg, x, Win, bin, stats + (i - 1) * 128, gam + (i - 1) * 64,
            bet + (i - 1) * 64, cW + i * 4096, hw, i > 0 ? 1 : 0);
        agg_kernel<<<2048, 256, 0, stream>>>((const unsigned int*)hw, sorted, offsets,
                                             degi, dinv, cb + i * 64, agg,
                                             stats + i * 128);
    }

    classifier<<<(NN + 255) / 256, 256, 0, stream>>>(agg, stats + 2 * 128, gam + 2 * 64,
                                                     bet + 2 * 64, W1, b1, W2, b2, out);
}